// Round 13
// baseline (172.591 us; speedup 1.0000x reference)
//
#include <hip/hip_runtime.h>
#include <math.h>

// N=2048, DH=256, DK=64, FF=32. fp32 in/out, f16 internal.
// ws layout (bytes):
//   q16  @ 0        : 2048x64   f16    (262144)
//   k16  @ 262144   : 2048x64   f16    (262144)
//   vT   @ 524288   : 256x2048  f16    (v transposed)  (1048576)
//   schl @ 1572864  : 2048x2048 f16x2  packed (score_hi, score_lo) (16777216)
//     -> focus (f16) overwrites first half of each schl row in-place;
//        k_feat reads it with row stride 2*NN halves.

#define NN  2048
#define DHH 256
#define DKK 64

typedef float    f32x4 __attribute__((ext_vector_type(4)));
typedef _Float16 f16x8 __attribute__((ext_vector_type(8)));
typedef _Float16 f16x4 __attribute__((ext_vector_type(4)));
typedef _Float16 f16x2 __attribute__((ext_vector_type(2)));
typedef int      i32x2 __attribute__((ext_vector_type(2)));
typedef int      i32x4 __attribute__((ext_vector_type(4)));

#define MFMA32(a, b, c) __builtin_amdgcn_mfma_f32_16x16x32_f16((a), (b), (c), 0, 0, 0)

// pack two f32 (RTZ) then relu the packed pair (v_cvt_pkrtz + v_pk_max_f16).
// Bit-identical to relu-then-pack: pkrtz(neg) is neg, max(.,0) -> +0.
__device__ __forceinline__ int rp2(float x, float y) {
    f16x2 v = __builtin_bit_cast(f16x2, __builtin_amdgcn_cvt_pkrtz(x, y));
    const f16x2 z = {(_Float16)0, (_Float16)0};
    v = __builtin_elementwise_max(v, z);
    return __builtin_bit_cast(int, v);
}

// ---------------------------------------------------------------------------
// K1: qkv projections (fp32 math). q,k stored f16 row-major; v stored f16
// transposed. grid (32, 6).
// ---------------------------------------------------------------------------
__global__ __launch_bounds__(256) void k_qkv(
    const float* __restrict__ x,
    const float* __restrict__ Wq, const float* __restrict__ bq,
    const float* __restrict__ Wk, const float* __restrict__ bk,
    const float* __restrict__ Wv, const float* __restrict__ bv,
    _Float16* __restrict__ q16, _Float16* __restrict__ k16,
    _Float16* __restrict__ vT)
{
    __shared__ float As[32][64];
    __shared__ float Bs[32][64];
    __shared__ _Float16 Ts[64 * 72];

    const int t  = threadIdx.x;
    const int m0 = blockIdx.x * 64;
    const int yb = blockIdx.y;

    const float* W; const float* bias; int wld; int cw0;
    if (yb == 0)      { W = Wq; bias = bq; wld = 64;  cw0 = 0; }
    else if (yb == 1) { W = Wk; bias = bk; wld = 64;  cw0 = 0; }
    else              { W = Wv; bias = bv; wld = 256; cw0 = (yb - 2) * 64; }

    const int tx = t & 15, ty = t >> 4;
    float acc[4][4] = {};

    for (int k0 = 0; k0 < DHH; k0 += 32) {
        {
            const int rr = t >> 3;
            const int cc = (t & 7) * 4;
            float4 a0 = *(const float4*)(x + (size_t)(m0 + rr)      * DHH + k0 + cc);
            float4 a1 = *(const float4*)(x + (size_t)(m0 + rr + 32) * DHH + k0 + cc);
            As[cc+0][rr]    = a0.x; As[cc+1][rr]    = a0.y; As[cc+2][rr]    = a0.z; As[cc+3][rr]    = a0.w;
            As[cc+0][rr+32] = a1.x; As[cc+1][rr+32] = a1.y; As[cc+2][rr+32] = a1.z; As[cc+3][rr+32] = a1.w;
        }
        {
            const int bk_ = t >> 4;
            const int bc  = (t & 15) * 4;
            *(float4*)&Bs[bk_][bc]      = *(const float4*)(W + (size_t)(k0 + bk_)      * wld + cw0 + bc);
            *(float4*)&Bs[bk_ + 16][bc] = *(const float4*)(W + (size_t)(k0 + bk_ + 16) * wld + cw0 + bc);
        }
        __syncthreads();
        #pragma unroll
        for (int kk = 0; kk < 32; ++kk) {
            float4 a = *(const float4*)&As[kk][ty * 4];
            float4 b = *(const float4*)&Bs[kk][tx * 4];
            float av[4] = {a.x, a.y, a.z, a.w};
            float bw[4] = {b.x, b.y, b.z, b.w};
            #pragma unroll
            for (int ii = 0; ii < 4; ++ii)
                #pragma unroll
                for (int jj = 0; jj < 4; ++jj)
                    acc[ii][jj] = fmaf(av[ii], bw[jj], acc[ii][jj]);
        }
        __syncthreads();
    }

    float4 b4 = *(const float4*)&bias[cw0 + tx * 4];
    float bc4[4] = {b4.x, b4.y, b4.z, b4.w};

    if (yb < 2) {
        _Float16* outp = (yb == 0) ? q16 : k16;
        #pragma unroll
        for (int ii = 0; ii < 4; ++ii) {
            f16x4 hv;
            #pragma unroll
            for (int jj = 0; jj < 4; ++jj) hv[jj] = (_Float16)(acc[ii][jj] + bc4[jj]);
            *(f16x4*)&outp[(size_t)(m0 + ty * 4 + ii) * 64 + tx * 4] = hv;
        }
    } else {
        #pragma unroll
        for (int jj = 0; jj < 4; ++jj) {
            f16x4 hv;
            #pragma unroll
            for (int ii = 0; ii < 4; ++ii) hv[ii] = (_Float16)(acc[ii][jj] + bc4[jj]);
            *(f16x4*)&Ts[(tx * 4 + jj) * 72 + ty * 4] = hv;
        }
        __syncthreads();
        {
            const int c = t >> 2, seg = t & 3;
            f16x8 r0 = *(const f16x8*)&Ts[c * 72 + seg * 16];
            f16x8 r1 = *(const f16x8*)&Ts[c * 72 + seg * 16 + 8];
            *(f16x8*)&vT[(size_t)(cw0 + c) * NN + m0 + seg * 16]     = r0;
            *(f16x8*)&vT[(size_t)(cw0 + c) * NN + m0 + seg * 16 + 8] = r1;
        }
    }
}

// ---------------------------------------------------------------------------
// K2: scores = k16 @ q16^T via f16 MFMA (dense). Packed (hi, lo) f16x2 out.
// ---------------------------------------------------------------------------
__global__ __launch_bounds__(256) void k_scores(
    const _Float16* __restrict__ q16, const _Float16* __restrict__ k16,
    f16x2* __restrict__ schl)
{
    const int t    = threadIdx.x;
    const int lane = t & 63;
    const int w    = t >> 6;
    const int col  = lane & 15;
    const int q    = lane >> 4;

    const int i0 = blockIdx.y * 128 + (w >> 1) * 64;
    const int j0 = blockIdx.x * 128 + (w & 1) * 64;

    f32x4 acc[4][4] = {};

    #pragma unroll
    for (int ks = 0; ks < 2; ++ks) {
        f16x8 a[4], b[4];
        #pragma unroll
        for (int f = 0; f < 4; ++f) {
            a[f] = *(const f16x8*)&k16[(size_t)(i0 + f * 16 + col) * 64 + ks * 32 + q * 8];
            b[f] = *(const f16x8*)&q16[(size_t)(j0 + f * 16 + col) * 64 + ks * 32 + q * 8];
        }
        #pragma unroll
        for (int fm = 0; fm < 4; ++fm)
            #pragma unroll
            for (int fn = 0; fn < 4; ++fn)
                acc[fm][fn] = MFMA32(a[fm], b[fn], acc[fm][fn]);
    }

    #pragma unroll
    for (int fm = 0; fm < 4; ++fm)
        #pragma unroll
        for (int fn = 0; fn < 4; ++fn)
            #pragma unroll
            for (int r = 0; r < 4; ++r) {
                const size_t idx = (size_t)(i0 + fm * 16 + q * 4 + r) * NN + j0 + fn * 16 + col;
                const float val = acc[fm][fn][r];
                const _Float16 h = (_Float16)val;
                f16x2 pk; pk[0] = h; pk[1] = (_Float16)(val - (float)h);
                schl[idx] = pk;
            }
}

// ---------------------------------------------------------------------------
// K3: per-edge MLP + row softmax. Zero LDS-pipe ops in the main loop.
// Change vs R12: EVEN/ODD output split per layer makes every layer a
// 16x16x32 MFMA with per-lane relu+pack hand-off:
//   C rows q*4+r of the (even, odd) MFMA pair pack to feats {8q+2r, 8q+2r+1}
//   == B k-slots k=8q+j of the next MFMA32. 5 unchained MFMA32 per st
//   (was 8 MFMA16 with two 2-deep chains). Same arithmetic terms.
// ---------------------------------------------------------------------------
__global__ __launch_bounds__(256) void k_mlp(
    const f16x2* __restrict__ schl,
    const float* __restrict__ adj, const float* __restrict__ dense,
    const float* __restrict__ W1, const float* __restrict__ b1,
    const float* __restrict__ W2, const float* __restrict__ b2,
    const float* __restrict__ W3,
    _Float16* __restrict__ focus)   // row stride 2*NN halves (overlays schl)
{
    __shared__ float red[8];

    const int t    = threadIdx.x;
    const int lane = t & 63;
    const int w    = t >> 6;
    const int col  = lane & 15;
    const int q    = lane >> 4;
    const int i    = blockIdx.x;

    // ---- layer-1 A frags (A[m=col][k=8q+j]); out-feat 2*col (even) / +1 (odd).
    //      k slots (q0 only): {W0hi, W0hi, W1_1, W1_2, W0lo, 0,0,0} pairing
    //      B1 = {shi, slo, a, d, shi, 0,0,0}.
    f16x8 l1Ae = {}, l1Ao = {};
    {
        const float w0e = W1[2 * col], w0o = W1[2 * col + 1];
        const _Float16 h0e = (_Float16)w0e, h0o = (_Float16)w0o;
        if (q == 0) {
            l1Ae[0] = h0e; l1Ae[1] = h0e;
            l1Ae[2] = (_Float16)W1[32 + 2 * col];
            l1Ae[3] = (_Float16)W1[64 + 2 * col];
            l1Ae[4] = (_Float16)(w0e - (float)h0e);
            l1Ao[0] = h0o; l1Ao[1] = h0o;
            l1Ao[2] = (_Float16)W1[32 + 2 * col + 1];
            l1Ao[3] = (_Float16)W1[64 + 2 * col + 1];
            l1Ao[4] = (_Float16)(w0o - (float)h0o);
        }
    }

    // ---- layer-2 A frags: w2Ae[j] = W2[8q+j][2*col], w2Ao[j] = W2[8q+j][2*col+1]
    f16x8 w2Ae, w2Ao;
    #pragma unroll
    for (int j = 0; j < 8; ++j) {
        w2Ae[j] = (_Float16)W2[(q * 8 + j) * 32 + 2 * col];
        w2Ao[j] = (_Float16)W2[(q * 8 + j) * 32 + 2 * col + 1];
    }

    // ---- layer-3 A frag (broadcast over m): a3[j] = W3[8q+j] ----
    f16x8 a3;
    #pragma unroll
    for (int j = 0; j < 8; ++j) a3[j] = (_Float16)W3[q * 8 + j];

    // ---- biases: C row q*4+r holds out-feat 8q+2r (even) / 8q+2r+1 (odd) ----
    f32x4 c1e, c1o, c2e, c2o;
    #pragma unroll
    for (int r = 0; r < 4; ++r) {
        c1e[r] = b1[q * 8 + 2 * r];
        c1o[r] = b1[q * 8 + 2 * r + 1];
        c2e[r] = b2[q * 8 + 2 * r];
        c2o[r] = b2[q * 8 + 2 * r + 1];
    }

    const f16x2* srow = schl  + (size_t)i * NN;
    const float* arow = adj   + (size_t)i * NN;
    const float* drow = dense + (size_t)i * NN;

    const f32x4 zero4 = {0.f, 0.f, 0.f, 0.f};
    float lg[8];

    for (int c = 0; c < 8; ++c) {
        const int base = w * 512 + c * 64;
        const int eb4  = base + col * 4;     // this lane's 4 edges (st=0..3)

        // one 16B load per operand per chunk (16 unique addrs, L1 broadcast)
        i32x4  sv = *(const i32x4*)&srow[eb4];      // 4x (shi, slo)
        float4 av = *(const float4*)&arow[eb4];
        float4 dv = *(const float4*)&drow[eb4];
        const float aa[4] = {av.x, av.y, av.z, av.w};
        const float dd[4] = {dv.x, dv.y, dv.z, dv.w};

        float lgc = 0.f;
        #pragma unroll
        for (int st = 0; st < 4; ++st) {
            const int d0 = sv[st];
            const int d1 = __builtin_bit_cast(int,
                __builtin_amdgcn_cvt_pkrtz(aa[st], dd[st]));

            i32x4 b1v;
            if (q == 0) { b1v[0] = d0; b1v[1] = d1; b1v[2] = d0 & 0xFFFF; b1v[3] = 0; }
            else        { b1v[0] = 0;  b1v[1] = 0;  b1v[2] = 0;           b1v[3] = 0; }
            f16x8 B1 = __builtin_bit_cast(f16x8, b1v);

            // ---- layer 1 (even / odd outs, independent) ----
            f32x4 h1e = MFMA32(l1Ae, B1, c1e);
            f32x4 h1o = MFMA32(l1Ao, B1, c1o);

            // pack: rows q*4+r -> feats {8q+2r, 8q+2r+1} == B k-slots 8q+j
            i32x4 p2 = { rp2(h1e[0], h1o[0]), rp2(h1e[1], h1o[1]),
                         rp2(h1e[2], h1o[2]), rp2(h1e[3], h1o[3]) };
            f16x8 B2 = __builtin_bit_cast(f16x8, p2);

            // ---- layer 2 (even / odd outs, independent) ----
            f32x4 h2e = MFMA32(w2Ae, B2, c2e);
            f32x4 h2o = MFMA32(w2Ao, B2, c2o);

            i32x4 p3 = { rp2(h2e[0], h2o[0]), rp2(h2e[1], h2o[1]),
                         rp2(h2e[2], h2o[2]), rp2(h2e[3], h2o[3]) };
            f16x8 B3 = __builtin_bit_cast(f16x8, p3);

            // ---- layer 3: logit(edge col) in every lane ----
            f32x4 c3 = MFMA32(a3, B3, zero4);
            lgc = (q == st) ? c3[0] : lgc;   // lane (q,col): edge base+4*col+q
        }
        lg[c] = lgc;
    }

    // ---- row softmax (edge = w*512 + c*64 + 4*col + q) ----
    float lmax = -1e30f;
    #pragma unroll
    for (int u = 0; u < 8; ++u) lmax = fmaxf(lmax, lg[u]);
    #pragma unroll
    for (int off = 32; off > 0; off >>= 1)
        lmax = fmaxf(lmax, __shfl_xor(lmax, off, 64));
    if (lane == 0) red[w] = lmax;
    __syncthreads();
    const float rmax = fmaxf(fmaxf(red[0], red[1]), fmaxf(red[2], red[3]));

    float lsum = 0.f;
    #pragma unroll
    for (int u = 0; u < 8; ++u) { lg[u] = __expf(lg[u] - rmax); lsum += lg[u]; }
    #pragma unroll
    for (int off = 32; off > 0; off >>= 1)
        lsum += __shfl_xor(lsum, off, 64);
    if (lane == 0) red[4 + w] = lsum;
    __syncthreads();
    const float inv = 1.f / (red[4] + red[5] + red[6] + red[7]);

    _Float16* hrow = focus + (size_t)i * 2 * NN;
    const int eb = w * 512 + 4 * col + q;
    #pragma unroll
    for (int u = 0; u < 8; ++u)
        hrow[eb + u * 64] = (_Float16)(lg[u] * inv);
}

// ---------------------------------------------------------------------------
// K4: feature = focus @ v via f16 MFMA, K split 4-way across waves + LDS
// reduce. grid (8,128). focus row stride = 2*NN halves (overlaid on schl).
// ---------------------------------------------------------------------------
__global__ __launch_bounds__(256) void k_feat(
    const _Float16* __restrict__ focus, const _Float16* __restrict__ vT,
    float* __restrict__ out)
{
    __shared__ float rbuf[3][64][8];

    const int t    = threadIdx.x;
    const int lane = t & 63;
    const int w    = t >> 6;
    const int col  = lane & 15;
    const int q    = lane >> 4;

    const int m0 = blockIdx.y * 16;
    const int n0 = blockIdx.x * 32;

    f32x4 acc0 = {}, acc1 = {};

    const size_t arow  = (size_t)(m0 + col) * (2 * NN);
    const size_t brow0 = (size_t)(n0 + col) * NN;
    const size_t brow1 = (size_t)(n0 + 16 + col) * NN;
    const int kb = w * 512 + q * 8;

    #pragma unroll 4
    for (int k0 = 0; k0 < 512; k0 += 32) {
        const int ko = kb + k0;
        f16x8 a  = *(const f16x8*)&focus[arow + ko];
        f16x8 b0 = *(const f16x8*)&vT[brow0 + ko];
        f16x8 b1 = *(const f16x8*)&vT[brow1 + ko];
        acc0 = MFMA32(a, b0, acc0);
        acc1 = MFMA32(a, b1, acc1);
    }

    if (w != 0) {
        *(float4*)&rbuf[w - 1][lane][0] = *(float4*)&acc0;
        *(float4*)&rbuf[w - 1][lane][4] = *(float4*)&acc1;
    }
    __syncthreads();

    if (w == 0) {
        #pragma unroll
        for (int j = 0; j < 3; ++j) {
            float4 p0 = *(const float4*)&rbuf[j][lane][0];
            float4 p1 = *(const float4*)&rbuf[j][lane][4];
            acc0[0] += p0.x; acc0[1] += p0.y; acc0[2] += p0.z; acc0[3] += p0.w;
            acc1[0] += p1.x; acc1[1] += p1.y; acc1[2] += p1.z; acc1[3] += p1.w;
        }
        #pragma unroll
        for (int r = 0; r < 4; ++r) {
            out[(size_t)(m0 + q * 4 + r) * DHH + n0 + col]      = acc0[r];
            out[(size_t)(m0 + q * 4 + r) * DHH + n0 + 16 + col] = acc1[r];
        }
    }
}

// ---------------------------------------------------------------------------
extern "C" void kernel_launch(void* const* d_in, const int* in_sizes, int n_in,
                              void* d_out, int out_size, void* d_ws, size_t ws_size,
                              hipStream_t stream) {
    const float* x     = (const float*)d_in[0];
    const float* adj   = (const float*)d_in[1];
    const float* dense = (const float*)d_in[2];
    const float* Wq    = (const float*)d_in[3];
    const float* bq    = (const float*)d_in[4];
    const float* Wk    = (const float*)d_in[5];
    const float* bk    = (const float*)d_in[6];
    const float* Wv    = (const float*)d_in[7];
    const float* bv    = (const float*)d_in[8];
    const float* W1    = (const float*)d_in[9];
    const float* b1    = (const float*)d_in[10];
    const float* W2    = (const float*)d_in[11];
    const float* b2    = (const float*)d_in[12];
    const float* W3    = (const float*)d_in[13];
    float* out = (float*)d_out;

    char* wsb = (char*)d_ws;
    _Float16* q16   = (_Float16*)(wsb);
    _Float16* k16   = (_Float16*)(wsb + 262144);
    _Float16* vT    = (_Float16*)(wsb + 524288);
    f16x2*    schl  = (f16x2*)   (wsb + 1572864);
    _Float16* focus = (_Float16*)(wsb + 1572864);   // row stride 2*NN, in-place

    hipLaunchKernelGGL(k_qkv,    dim3(32, 6),  dim3(256), 0, stream,
                       x, Wq, bq, Wk, bk, Wv, bv, q16, k16, vT);
    hipLaunchKernelGGL(k_scores, dim3(16, 16), dim3(256), 0, stream, q16, k16, schl);
    hipLaunchKernelGGL(k_mlp,    dim3(2048),   dim3(256), 0, stream,
                       schl, adj, dense, W1, b1, W2, b2, W3, focus);
    hipLaunchKernelGGL(k_feat,   dim3(8, 128), dim3(256), 0, stream,
                       focus, vT, out);
}

// Round 14
// 171.793 us; speedup vs baseline: 1.0046x; 1.0046x over previous
//
#include <hip/hip_runtime.h>
#include <math.h>

// N=2048, DH=256, DK=64, FF=32. fp32 in/out, f16 internal.
// ws layout (bytes):
//   q16   @ 0       : 2048x64   f16  (262144)
//   k16   @ 262144  : 2048x64   f16  (262144)
//   vT    @ 524288  : 256x2048  f16  (v transposed)  (1048576)
//   sc16  @ 1572864 : 2048x2048 f16  scores (plain f16 — R2-empirical: the
//                     absmax floor is set by focus-f16, not score precision)
//   focus @ 9961472 : 2048x2048 f16  compact, stride NN
// total ~18.3 MB.

#define NN  2048
#define DHH 256
#define DKK 64

typedef float    f32x4 __attribute__((ext_vector_type(4)));
typedef _Float16 f16x8 __attribute__((ext_vector_type(8)));
typedef _Float16 f16x4 __attribute__((ext_vector_type(4)));
typedef _Float16 f16x2 __attribute__((ext_vector_type(2)));
typedef int      i32x2 __attribute__((ext_vector_type(2)));
typedef int      i32x4 __attribute__((ext_vector_type(4)));

#define MFMA32(a, b, c) __builtin_amdgcn_mfma_f32_16x16x32_f16((a), (b), (c), 0, 0, 0)

// pack two f32 (RTZ) then relu the packed pair. Bit-identical to
// relu-then-pack: pkrtz(neg) is neg, max(.,0) -> +0.
__device__ __forceinline__ int rp2(float x, float y) {
    f16x2 v = __builtin_bit_cast(f16x2, __builtin_amdgcn_cvt_pkrtz(x, y));
    const f16x2 z = {(_Float16)0, (_Float16)0};
    v = __builtin_elementwise_max(v, z);
    return __builtin_bit_cast(int, v);
}

// ---------------------------------------------------------------------------
// K1: qkv projections (fp32 math). q,k stored f16 row-major; v stored f16
// transposed. grid (32, 6).
// ---------------------------------------------------------------------------
__global__ __launch_bounds__(256) void k_qkv(
    const float* __restrict__ x,
    const float* __restrict__ Wq, const float* __restrict__ bq,
    const float* __restrict__ Wk, const float* __restrict__ bk,
    const float* __restrict__ Wv, const float* __restrict__ bv,
    _Float16* __restrict__ q16, _Float16* __restrict__ k16,
    _Float16* __restrict__ vT)
{
    __shared__ float As[32][64];
    __shared__ float Bs[32][64];
    __shared__ _Float16 Ts[64 * 72];

    const int t  = threadIdx.x;
    const int m0 = blockIdx.x * 64;
    const int yb = blockIdx.y;

    const float* W; const float* bias; int wld; int cw0;
    if (yb == 0)      { W = Wq; bias = bq; wld = 64;  cw0 = 0; }
    else if (yb == 1) { W = Wk; bias = bk; wld = 64;  cw0 = 0; }
    else              { W = Wv; bias = bv; wld = 256; cw0 = (yb - 2) * 64; }

    const int tx = t & 15, ty = t >> 4;
    float acc[4][4] = {};

    for (int k0 = 0; k0 < DHH; k0 += 32) {
        {
            const int rr = t >> 3;
            const int cc = (t & 7) * 4;
            float4 a0 = *(const float4*)(x + (size_t)(m0 + rr)      * DHH + k0 + cc);
            float4 a1 = *(const float4*)(x + (size_t)(m0 + rr + 32) * DHH + k0 + cc);
            As[cc+0][rr]    = a0.x; As[cc+1][rr]    = a0.y; As[cc+2][rr]    = a0.z; As[cc+3][rr]    = a0.w;
            As[cc+0][rr+32] = a1.x; As[cc+1][rr+32] = a1.y; As[cc+2][rr+32] = a1.z; As[cc+3][rr+32] = a1.w;
        }
        {
            const int bk_ = t >> 4;
            const int bc  = (t & 15) * 4;
            *(float4*)&Bs[bk_][bc]      = *(const float4*)(W + (size_t)(k0 + bk_)      * wld + cw0 + bc);
            *(float4*)&Bs[bk_ + 16][bc] = *(const float4*)(W + (size_t)(k0 + bk_ + 16) * wld + cw0 + bc);
        }
        __syncthreads();
        #pragma unroll
        for (int kk = 0; kk < 32; ++kk) {
            float4 a = *(const float4*)&As[kk][ty * 4];
            float4 b = *(const float4*)&Bs[kk][tx * 4];
            float av[4] = {a.x, a.y, a.z, a.w};
            float bw[4] = {b.x, b.y, b.z, b.w};
            #pragma unroll
            for (int ii = 0; ii < 4; ++ii)
                #pragma unroll
                for (int jj = 0; jj < 4; ++jj)
                    acc[ii][jj] = fmaf(av[ii], bw[jj], acc[ii][jj]);
        }
        __syncthreads();
    }

    float4 b4 = *(const float4*)&bias[cw0 + tx * 4];
    float bc4[4] = {b4.x, b4.y, b4.z, b4.w};

    if (yb < 2) {
        _Float16* outp = (yb == 0) ? q16 : k16;
        #pragma unroll
        for (int ii = 0; ii < 4; ++ii) {
            f16x4 hv;
            #pragma unroll
            for (int jj = 0; jj < 4; ++jj) hv[jj] = (_Float16)(acc[ii][jj] + bc4[jj]);
            *(f16x4*)&outp[(size_t)(m0 + ty * 4 + ii) * 64 + tx * 4] = hv;
        }
    } else {
        #pragma unroll
        for (int jj = 0; jj < 4; ++jj) {
            f16x4 hv;
            #pragma unroll
            for (int ii = 0; ii < 4; ++ii) hv[ii] = (_Float16)(acc[ii][jj] + bc4[jj]);
            *(f16x4*)&Ts[(tx * 4 + jj) * 72 + ty * 4] = hv;
        }
        __syncthreads();
        {
            const int c = t >> 2, seg = t & 3;
            f16x8 r0 = *(const f16x8*)&Ts[c * 72 + seg * 16];
            f16x8 r1 = *(const f16x8*)&Ts[c * 72 + seg * 16 + 8];
            *(f16x8*)&vT[(size_t)(cw0 + c) * NN + m0 + seg * 16]     = r0;
            *(f16x8*)&vT[(size_t)(cw0 + c) * NN + m0 + seg * 16 + 8] = r1;
        }
    }
}

// ---------------------------------------------------------------------------
// K2: scores = k16 @ q16^T via f16 MFMA (dense). Plain f16 score out.
// ---------------------------------------------------------------------------
__global__ __launch_bounds__(256) void k_scores(
    const _Float16* __restrict__ q16, const _Float16* __restrict__ k16,
    _Float16* __restrict__ sc16)
{
    const int t    = threadIdx.x;
    const int lane = t & 63;
    const int w    = t >> 6;
    const int col  = lane & 15;
    const int q    = lane >> 4;

    const int i0 = blockIdx.y * 128 + (w >> 1) * 64;
    const int j0 = blockIdx.x * 128 + (w & 1) * 64;

    f32x4 acc[4][4] = {};

    #pragma unroll
    for (int ks = 0; ks < 2; ++ks) {
        f16x8 a[4], b[4];
        #pragma unroll
        for (int f = 0; f < 4; ++f) {
            a[f] = *(const f16x8*)&k16[(size_t)(i0 + f * 16 + col) * 64 + ks * 32 + q * 8];
            b[f] = *(const f16x8*)&q16[(size_t)(j0 + f * 16 + col) * 64 + ks * 32 + q * 8];
        }
        #pragma unroll
        for (int fm = 0; fm < 4; ++fm)
            #pragma unroll
            for (int fn = 0; fn < 4; ++fn)
                acc[fm][fn] = MFMA32(a[fm], b[fn], acc[fm][fn]);
    }

    #pragma unroll
    for (int fm = 0; fm < 4; ++fm)
        #pragma unroll
        for (int fn = 0; fn < 4; ++fn)
            #pragma unroll
            for (int r = 0; r < 4; ++r)
                sc16[(size_t)(i0 + fm * 16 + q * 4 + r) * NN + j0 + fn * 16 + col] =
                    (_Float16)acc[fm][fn][r];
}

// ---------------------------------------------------------------------------
// K3: per-edge MLP + row softmax. Zero LDS-pipe ops in the main loop.
// vs R13: plain f16 scores (no hi/lo, no W0lo compensation slot) —
// B1 k-slots {s, a, d}. All-MFMA32 even/odd structure unchanged.
// ---------------------------------------------------------------------------
__global__ __launch_bounds__(256) void k_mlp(
    const _Float16* __restrict__ sc16,
    const float* __restrict__ adj, const float* __restrict__ dense,
    const float* __restrict__ W1, const float* __restrict__ b1,
    const float* __restrict__ W2, const float* __restrict__ b2,
    const float* __restrict__ W3,
    _Float16* __restrict__ focus)   // compact, stride NN
{
    __shared__ float red[8];

    const int t    = threadIdx.x;
    const int lane = t & 63;
    const int w    = t >> 6;
    const int col  = lane & 15;
    const int q    = lane >> 4;
    const int i    = blockIdx.x;

    // ---- layer-1 A frags: k slots (q0 only) {W1_0, W1_1, W1_2, 0...}
    //      pairing B1 = {s, a, d, 0...}; even col 2*col, odd col 2*col+1.
    f16x8 l1Ae = {}, l1Ao = {};
    if (q == 0) {
        l1Ae[0] = (_Float16)W1[2 * col];
        l1Ae[1] = (_Float16)W1[32 + 2 * col];
        l1Ae[2] = (_Float16)W1[64 + 2 * col];
        l1Ao[0] = (_Float16)W1[2 * col + 1];
        l1Ao[1] = (_Float16)W1[32 + 2 * col + 1];
        l1Ao[2] = (_Float16)W1[64 + 2 * col + 1];
    }

    // ---- layer-2 A frags: w2Ae[j]=W2[8q+j][2col], w2Ao[j]=W2[8q+j][2col+1] ----
    f16x8 w2Ae, w2Ao;
    #pragma unroll
    for (int j = 0; j < 8; ++j) {
        w2Ae[j] = (_Float16)W2[(q * 8 + j) * 32 + 2 * col];
        w2Ao[j] = (_Float16)W2[(q * 8 + j) * 32 + 2 * col + 1];
    }

    // ---- layer-3 A frag (broadcast over m): a3[j] = W3[8q+j] ----
    f16x8 a3;
    #pragma unroll
    for (int j = 0; j < 8; ++j) a3[j] = (_Float16)W3[q * 8 + j];

    // ---- biases: C row q*4+r holds out-feat 8q+2r (even) / +1 (odd) ----
    f32x4 c1e, c1o, c2e, c2o;
    #pragma unroll
    for (int r = 0; r < 4; ++r) {
        c1e[r] = b1[q * 8 + 2 * r];
        c1o[r] = b1[q * 8 + 2 * r + 1];
        c2e[r] = b2[q * 8 + 2 * r];
        c2o[r] = b2[q * 8 + 2 * r + 1];
    }

    const _Float16* srow = sc16  + (size_t)i * NN;
    const float*    arow = adj   + (size_t)i * NN;
    const float*    drow = dense + (size_t)i * NN;

    const f32x4 zero4 = {0.f, 0.f, 0.f, 0.f};
    float lg[8];

    for (int c = 0; c < 8; ++c) {
        const int base = w * 512 + c * 64;
        const int eb4  = base + col * 4;     // this lane's 4 edges (st=0..3)

        // one 8B + two 16B loads per chunk (16 unique addrs, L1 broadcast)
        i32x2  sv = *(const i32x2*)&srow[eb4];      // 4x f16 score
        float4 av = *(const float4*)&arow[eb4];
        float4 dv = *(const float4*)&drow[eb4];
        const float aa[4] = {av.x, av.y, av.z, av.w};
        const float dd[4] = {dv.x, dv.y, dv.z, dv.w};

        float lgc = 0.f;
        #pragma unroll
        for (int st = 0; st < 4; ++st) {
            const int sd  = sv[st >> 1];
            const int s16 = (st & 1) ? ((unsigned)sd >> 16) : (sd & 0xFFFF);
            const int pk  = __builtin_bit_cast(int,
                __builtin_amdgcn_cvt_pkrtz(aa[st], dd[st]));   // (a, d)

            i32x4 b1v;
            if (q == 0) {
                b1v[0] = (pk << 16) | s16;        // (s, a)
                b1v[1] = (unsigned)pk >> 16;      // (d, 0)
                b1v[2] = 0; b1v[3] = 0;
            } else {
                b1v[0] = 0; b1v[1] = 0; b1v[2] = 0; b1v[3] = 0;
            }
            f16x8 B1 = __builtin_bit_cast(f16x8, b1v);

            // ---- layer 1 (even / odd outs, independent) ----
            f32x4 h1e = MFMA32(l1Ae, B1, c1e);
            f32x4 h1o = MFMA32(l1Ao, B1, c1o);

            // pack: rows q*4+r -> feats {8q+2r, 8q+2r+1} == B k-slots 8q+j
            i32x4 p2 = { rp2(h1e[0], h1o[0]), rp2(h1e[1], h1o[1]),
                         rp2(h1e[2], h1o[2]), rp2(h1e[3], h1o[3]) };
            f16x8 B2 = __builtin_bit_cast(f16x8, p2);

            // ---- layer 2 (even / odd outs, independent) ----
            f32x4 h2e = MFMA32(w2Ae, B2, c2e);
            f32x4 h2o = MFMA32(w2Ao, B2, c2o);

            i32x4 p3 = { rp2(h2e[0], h2o[0]), rp2(h2e[1], h2o[1]),
                         rp2(h2e[2], h2o[2]), rp2(h2e[3], h2o[3]) };
            f16x8 B3 = __builtin_bit_cast(f16x8, p3);

            // ---- layer 3: logit(edge col) in every lane ----
            f32x4 c3 = MFMA32(a3, B3, zero4);
            lgc = (q == st) ? c3[0] : lgc;   // lane (q,col): edge base+4*col+q
        }
        lg[c] = lgc;
    }

    // ---- row softmax (edge = w*512 + c*64 + 4*col + q) ----
    float lmax = -1e30f;
    #pragma unroll
    for (int u = 0; u < 8; ++u) lmax = fmaxf(lmax, lg[u]);
    #pragma unroll
    for (int off = 32; off > 0; off >>= 1)
        lmax = fmaxf(lmax, __shfl_xor(lmax, off, 64));
    if (lane == 0) red[w] = lmax;
    __syncthreads();
    const float rmax = fmaxf(fmaxf(red[0], red[1]), fmaxf(red[2], red[3]));

    float lsum = 0.f;
    #pragma unroll
    for (int u = 0; u < 8; ++u) { lg[u] = __expf(lg[u] - rmax); lsum += lg[u]; }
    #pragma unroll
    for (int off = 32; off > 0; off >>= 1)
        lsum += __shfl_xor(lsum, off, 64);
    if (lane == 0) red[4 + w] = lsum;
    __syncthreads();
    const float inv = 1.f / (red[4] + red[5] + red[6] + red[7]);

    _Float16* hrow = focus + (size_t)i * NN;
    const int eb = w * 512 + 4 * col + q;
    #pragma unroll
    for (int u = 0; u < 8; ++u)
        hrow[eb + u * 64] = (_Float16)(lg[u] * inv);
}

// ---------------------------------------------------------------------------
// K4: feature = focus @ v via f16 MFMA, K split 4-way across waves + LDS
// reduce. grid (8,128). focus compact (stride NN).
// ---------------------------------------------------------------------------
__global__ __launch_bounds__(256) void k_feat(
    const _Float16* __restrict__ focus, const _Float16* __restrict__ vT,
    float* __restrict__ out)
{
    __shared__ float rbuf[3][64][8];

    const int t    = threadIdx.x;
    const int lane = t & 63;
    const int w    = t >> 6;
    const int col  = lane & 15;
    const int q    = lane >> 4;

    const int m0 = blockIdx.y * 16;
    const int n0 = blockIdx.x * 32;

    f32x4 acc0 = {}, acc1 = {};

    const size_t arow  = (size_t)(m0 + col) * NN;
    const size_t brow0 = (size_t)(n0 + col) * NN;
    const size_t brow1 = (size_t)(n0 + 16 + col) * NN;
    const int kb = w * 512 + q * 8;

    #pragma unroll 4
    for (int k0 = 0; k0 < 512; k0 += 32) {
        const int ko = kb + k0;
        f16x8 a  = *(const f16x8*)&focus[arow + ko];
        f16x8 b0 = *(const f16x8*)&vT[brow0 + ko];
        f16x8 b1 = *(const f16x8*)&vT[brow1 + ko];
        acc0 = MFMA32(a, b0, acc0);
        acc1 = MFMA32(a, b1, acc1);
    }

    if (w != 0) {
        *(float4*)&rbuf[w - 1][lane][0] = *(float4*)&acc0;
        *(float4*)&rbuf[w - 1][lane][4] = *(float4*)&acc1;
    }
    __syncthreads();

    if (w == 0) {
        #pragma unroll
        for (int j = 0; j < 3; ++j) {
            float4 p0 = *(const float4*)&rbuf[j][lane][0];
            float4 p1 = *(const float4*)&rbuf[j][lane][4];
            acc0[0] += p0.x; acc0[1] += p0.y; acc0[2] += p0.z; acc0[3] += p0.w;
            acc1[0] += p1.x; acc1[1] += p1.y; acc1[2] += p1.z; acc1[3] += p1.w;
        }
        #pragma unroll
        for (int r = 0; r < 4; ++r) {
            out[(size_t)(m0 + q * 4 + r) * DHH + n0 + col]      = acc0[r];
            out[(size_t)(m0 + q * 4 + r) * DHH + n0 + 16 + col] = acc1[r];
        }
    }
}

// ---------------------------------------------------------------------------
extern "C" void kernel_launch(void* const* d_in, const int* in_sizes, int n_in,
                              void* d_out, int out_size, void* d_ws, size_t ws_size,
                              hipStream_t stream) {
    const float* x     = (const float*)d_in[0];
    const float* adj   = (const float*)d_in[1];
    const float* dense = (const float*)d_in[2];
    const float* Wq    = (const float*)d_in[3];
    const float* bq    = (const float*)d_in[4];
    const float* Wk    = (const float*)d_in[5];
    const float* bk    = (const float*)d_in[6];
    const float* Wv    = (const float*)d_in[7];
    const float* bv    = (const float*)d_in[8];
    const float* W1    = (const float*)d_in[9];
    const float* b1    = (const float*)d_in[10];
    const float* W2    = (const float*)d_in[11];
    const float* b2    = (const float*)d_in[12];
    const float* W3    = (const float*)d_in[13];
    float* out = (float*)d_out;

    char* wsb = (char*)d_ws;
    _Float16* q16   = (_Float16*)(wsb);
    _Float16* k16   = (_Float16*)(wsb + 262144);
    _Float16* vT    = (_Float16*)(wsb + 524288);
    _Float16* sc16  = (_Float16*)(wsb + 1572864);
    _Float16* focus = (_Float16*)(wsb + 9961472);

    hipLaunchKernelGGL(k_qkv,    dim3(32, 6),  dim3(256), 0, stream,
                       x, Wq, bq, Wk, bk, Wv, bv, q16, k16, vT);
    hipLaunchKernelGGL(k_scores, dim3(16, 16), dim3(256), 0, stream, q16, k16, sc16);
    hipLaunchKernelGGL(k_mlp,    dim3(2048),   dim3(256), 0, stream,
                       sc16, adj, dense, W1, b1, W2, b2, W3, focus);
    hipLaunchKernelGGL(k_feat,   dim3(8, 128), dim3(256), 0, stream,
                       focus, vT, out);
}